// Round 1
// baseline (390.022 us; speedup 1.0000x reference)
//
#include <hip/hip_runtime.h>
#include <hip/hip_bf16.h>

// Problem constants (from reference):
//   B=64, C=256, H=W=56  -> HW=3136 (=784 float4), SQ=64
//   x: [B,C,H,W] f32; w1: [SQ,C]; b1: [SQ]; w2: [C,SQ]; b2: [C]
#define SE_B   64
#define SE_C   256
#define SE_SQ  64
#define SE_HW  3136
#define SE_HW4 784   // float4s per plane

// ---------------------------------------------------------------------------
// Kernel 1: global average pool. One block per (b,c) plane (16384 blocks).
// Plane is contiguous -> float4 coalesced loads, block reduction.
// ---------------------------------------------------------------------------
__global__ __launch_bounds__(256) void se_pool(const float* __restrict__ x,
                                               float* __restrict__ s) {
    const int plane = blockIdx.x;                  // b*C + c
    const float4* xp = (const float4*)(x + (size_t)plane * SE_HW);

    float sum = 0.0f;
    for (int i = threadIdx.x; i < SE_HW4; i += 256) {
        float4 v = xp[i];
        sum += (v.x + v.y) + (v.z + v.w);
    }

    // wave (64-lane) shuffle reduction, then cross-wave via LDS
    for (int off = 32; off > 0; off >>= 1)
        sum += __shfl_down(sum, off, 64);

    __shared__ float red[4];
    const int wave = threadIdx.x >> 6;
    const int lane = threadIdx.x & 63;
    if (lane == 0) red[wave] = sum;
    __syncthreads();
    if (threadIdx.x == 0) {
        float t = (red[0] + red[1]) + (red[2] + red[3]);
        s[plane] = t * (1.0f / (float)SE_HW);
    }
}

// ---------------------------------------------------------------------------
// Kernel 2: excitation MLP. One block per batch (64 blocks, 256 threads).
//   h = relu(w1 @ s_b + b1)   [SQ]
//   g = sigmoid(w2 @ h + b2)  [C]
// Tiny compute (~4 MFLOP total across the grid) — latency-bound, negligible.
// ---------------------------------------------------------------------------
__global__ __launch_bounds__(256) void se_fc(const float* __restrict__ s,
                                             const float* __restrict__ w1,
                                             const float* __restrict__ b1,
                                             const float* __restrict__ w2,
                                             const float* __restrict__ b2,
                                             float* __restrict__ g) {
    const int b = blockIdx.x;
    __shared__ float s_sh[SE_C];
    __shared__ float h_sh[SE_SQ];

    s_sh[threadIdx.x] = s[b * SE_C + threadIdx.x];
    __syncthreads();

    if (threadIdx.x < SE_SQ) {
        float acc = b1[threadIdx.x];
        const float* w = w1 + (size_t)threadIdx.x * SE_C;
        #pragma unroll 8
        for (int c = 0; c < SE_C; ++c) acc = fmaf(w[c], s_sh[c], acc);
        h_sh[threadIdx.x] = fmaxf(acc, 0.0f);
    }
    __syncthreads();

    float acc = b2[threadIdx.x];
    const float* w = w2 + (size_t)threadIdx.x * SE_SQ;
    #pragma unroll 8
    for (int k = 0; k < SE_SQ; ++k) acc = fmaf(w[k], h_sh[k], acc);
    g[b * SE_C + threadIdx.x] = 1.0f / (1.0f + __expf(-acc));
}

// ---------------------------------------------------------------------------
// Kernel 3: broadcast scale. One block per (b,c) plane; float4 in/out.
// ---------------------------------------------------------------------------
__global__ __launch_bounds__(256) void se_scale(const float* __restrict__ x,
                                                const float* __restrict__ g,
                                                float* __restrict__ out) {
    const int plane = blockIdx.x;
    const float gv = g[plane];
    const float4* xp = (const float4*)(x + (size_t)plane * SE_HW);
    float4* op = (float4*)(out + (size_t)plane * SE_HW);
    for (int i = threadIdx.x; i < SE_HW4; i += 256) {
        float4 v = xp[i];
        v.x *= gv; v.y *= gv; v.z *= gv; v.w *= gv;
        op[i] = v;
    }
}

extern "C" void kernel_launch(void* const* d_in, const int* in_sizes, int n_in,
                              void* d_out, int out_size, void* d_ws, size_t ws_size,
                              hipStream_t stream) {
    const float* x  = (const float*)d_in[0];
    const float* w1 = (const float*)d_in[1];
    const float* b1 = (const float*)d_in[2];
    const float* w2 = (const float*)d_in[3];
    const float* b2 = (const float*)d_in[4];
    float* out = (float*)d_out;

    // workspace layout: s[B*C] then g[B*C]  (32 KB of the ws; overwritten fully
    // before being read, so 0xAA poison is harmless)
    float* s = (float*)d_ws;
    float* g = s + SE_B * SE_C;

    se_pool <<<SE_B * SE_C, 256, 0, stream>>>(x, s);
    se_fc   <<<SE_B,        256, 0, stream>>>(s, w1, b1, w2, b2, g);
    se_scale<<<SE_B * SE_C, 256, 0, stream>>>(x, g, out);
}